// Round 13
// baseline (363.524 us; speedup 1.0000x reference)
//
#include <hip/hip_runtime.h>

typedef __attribute__((ext_vector_type(8))) short short8;
typedef __attribute__((ext_vector_type(4))) float f32x4;
typedef __attribute__((ext_vector_type(16))) float f32x16;

#define DEV __device__ __forceinline__

DEV unsigned short f2bf(float f) {
  unsigned int u; __builtin_memcpy(&u, &f, 4);
  u = (u + 0x7FFFu + ((u >> 16) & 1u)) >> 16;
  return (unsigned short)u;
}
DEV float bf2f(unsigned short h) {
  unsigned int u = ((unsigned int)h) << 16;
  float f; __builtin_memcpy(&f, &u, 4);
  return f;
}
DEV unsigned int cvtpk(float lo, float hi_) {
  unsigned int r;
  asm("v_cvt_pk_bf16_f32 %0, %1, %2" : "=v"(r) : "v"(lo), "v"(hi_));
  return r;
}

DEV void gload_lds16(const void* g, void* l) {
  __builtin_amdgcn_global_load_lds(
      (const __attribute__((address_space(1))) void*)g,
      (__attribute__((address_space(3))) void*)l, 16, 0, 0);
}

DEV f32x16 mfma32(short8 a, short8 b, f32x16 c) {
  return __builtin_amdgcn_mfma_f32_32x32x16_bf16(a, b, c, 0, 0, 0);
}
DEV f32x4 mfma16(short8 a, short8 b, f32x4 c) {
  return __builtin_amdgcn_mfma_f32_16x16x32_bf16(a, b, c, 0, 0, 0);
}

// GEMM LDS swizzle: unit'' = u ^ (row&7) ^ (((row>>3)&1)<<1).
// For 32-row b128 column reads only (r, r+16) share a bank-quad -> 2-way (free).
// 16-row reads and 8-row staging stripes stay <=2-way. Involution in u.
DEV int USW(int u, int row) { return u ^ (row & 7) ^ (((row >> 3) & 1) << 1); }

// ---------------------------------------------------------------------------
// K1: fp32 c,x -> bf16 concat tb [4096][2048]
// ---------------------------------------------------------------------------
__global__ __launch_bounds__(256) void conv_tb(const float* __restrict__ c,
                                               const float* __restrict__ x,
                                               unsigned short* __restrict__ tb) {
  int row = blockIdx.x;
  int b = row >> 11, s = row & 2047;
  const float* src = (s < 256) ? (c + (size_t)(b * 256 + s) * 2048)
                               : (x + (size_t)(b * 1792 + (s - 256)) * 2048);
  int t = threadIdx.x;
  float4 v0 = *(const float4*)&src[t * 8];
  float4 v1 = *(const float4*)&src[t * 8 + 4];
  union { unsigned short us[8]; uint4 u; } pk;
  pk.us[0] = f2bf(v0.x); pk.us[1] = f2bf(v0.y); pk.us[2] = f2bf(v0.z); pk.us[3] = f2bf(v0.w);
  pk.us[4] = f2bf(v1.x); pk.us[5] = f2bf(v1.y); pk.us[6] = f2bf(v1.z); pk.us[7] = f2bf(v1.w);
  *(uint4*)&tb[(size_t)row * 2048 + t * 8] = pk.u;
}

// ---------------------------------------------------------------------------
// K2: transpose+convert 8 weights: W [K][N] f32 -> Wt [N][K] bf16
// ---------------------------------------------------------------------------
__global__ __launch_bounds__(256) void trans_w(
    const float* __restrict__ w0, const float* __restrict__ w1,
    const float* __restrict__ w2, const float* __restrict__ w3,
    const float* __restrict__ w4, const float* __restrict__ w5,
    const float* __restrict__ w6, const float* __restrict__ w7,
    unsigned short* __restrict__ dstbase) {
  const float* W;
  switch (blockIdx.z) {
    case 0: W = w0; break; case 1: W = w1; break; case 2: W = w2; break; case 3: W = w3; break;
    case 4: W = w4; break; case 5: W = w5; break; case 6: W = w6; break; default: W = w7; break;
  }
  unsigned short* Wt = dstbase + (size_t)blockIdx.z * 2048 * 2048;
  __shared__ float tile[64][65];
  int n0 = blockIdx.x * 64, k0 = blockIdx.y * 64;
  int j = threadIdx.x & 63, i0 = threadIdx.x >> 6;
#pragma unroll
  for (int p = 0; p < 16; ++p) {
    int i = i0 + p * 4;
    tile[i][j] = W[(size_t)(k0 + i) * 2048 + n0 + j];
  }
  __syncthreads();
#pragma unroll
  for (int p = 0; p < 16; ++p) {
    int i = i0 + p * 4;
    Wt[(size_t)(n0 + i) * 2048 + k0 + j] = f2bf(tile[j][i]);
  }
}

// ---------------------------------------------------------------------------
// K3: fused QKV GEMM, 256x256, BK=64, 8 waves, R6 4-phase schedule.
// R13: mfma_f32_32x32x16_bf16 inner compute (R9) + CORRECTED double-XOR
// swizzle USW (R9's u^(row&7) aliased lanes r,r+8,r+16,r+24 4-way on 32-row
// reads; USW leaves only (r,r+16) sharing a bank-quad = 2-way = free).
// Fragment maps validated on-device by R9 (passed): A/B row|col = lane&31,
// k = (lane>>5)*8+j; C col = lane&31, row = (reg&3)+8*(reg>>2)+4*(lane>>5).
// ---------------------------------------------------------------------------
DEV void stage_A8(char* ldsAbase, const unsigned short* gtile, int mh, int wid, int lane) {
#pragma unroll
  for (int p = 0; p < 2; ++p) {
    int row0 = mh * 64 + p * 128 + wid * 8;  // wave-uniform
    int row = row0 + (lane >> 3);
    int u = USW(lane & 7, row);
    gload_lds16(gtile + (size_t)row * 2048 + u * 8, ldsAbase + row0 * 128);
  }
}
DEV void stage_B8(char* ldsBbase, const unsigned short* gtile, int nh, int wid, int lane) {
#pragma unroll
  for (int p = 0; p < 2; ++p) {
    int idx = p * 8 + wid;
    int row0 = (idx >> 2) * 64 + nh * 32 + (idx & 3) * 8;  // wave-uniform
    int row = row0 + (lane >> 3);
    int u = USW(lane & 7, row);
    gload_lds16(gtile + (size_t)row * 2048 + u * 8, ldsBbase + row0 * 128);
  }
}

__global__ __launch_bounds__(512, 2) void gemm_qkv3_8ph(
    const unsigned short* __restrict__ A,
    const unsigned short* __restrict__ Wt,
    unsigned short* __restrict__ out) {
  extern __shared__ __align__(16) char ldsc[];
  const size_t M2 = 2048ull * 2048ull;
  int bid = blockIdx.x;
  int sw = (bid & 7) * 48 + (bid >> 3);   // bijective XCD swizzle (384 % 8 == 0)
  const int which = sw >> 7;
  const int rem = sw & 127;
  const int m0 = (rem >> 3) * 256, n0 = (rem & 7) * 256;
  const unsigned short* Bt = Wt + (size_t)(((m0 & 2047) < 256) ? which : which + 4) * M2;
  unsigned short* C = out + (size_t)which * (4096ull * 2048ull);
  const int tid = threadIdx.x, wid = tid >> 6, lane = tid & 63;
  const int l31 = lane & 31, hi = lane >> 5;
  const int wm = wid >> 2, wn = wid & 3;
  const unsigned short* gA = A + (size_t)m0 * 2048;
  const unsigned short* gB = Bt + (size_t)n0 * 2048;

  f32x16 acc[4][2] = {};   // [mh*2+mt][nh]
  short8 af[2][4], bf0[4], bf1[4];

#define READ_AF(Abase, mh)                                                           \
  _Pragma("unroll") for (int mt = 0; mt < 2; ++mt)                                   \
  _Pragma("unroll") for (int s = 0; s < 4; ++s) {                                    \
    int row = wm * 128 + (mh) * 64 + mt * 32 + l31;                                  \
    af[mt][s] = *(const short8*)((Abase) + row * 128 + (USW(s * 2 + hi, row) << 4)); \
  }
#define READ_BF(Bbase, nh, dst)                                                      \
  _Pragma("unroll") for (int s = 0; s < 4; ++s) {                                    \
    int row = wn * 64 + (nh) * 32 + l31;                                             \
    dst[s] = *(const short8*)((Bbase) + row * 128 + (USW(s * 2 + hi, row) << 4));    \
  }
#define MFMA_Q(mhb, BF, nh)                                                          \
  _Pragma("unroll") for (int mt = 0; mt < 2; ++mt)                                   \
  _Pragma("unroll") for (int s = 0; s < 4; ++s)                                      \
    acc[(mhb) * 2 + mt][nh] = mfma32(af[mt][s], BF[s], acc[(mhb) * 2 + mt][nh]);

  // prologue: tile0 fully + A1mh0/B1nh0; counted wait
  stage_A8(ldsc, gA, 0, wid, lane);
  stage_A8(ldsc, gA, 1, wid, lane);
  stage_B8(ldsc + 32768, gB, 0, wid, lane);
  stage_B8(ldsc + 32768, gB, 1, wid, lane);
  stage_A8(ldsc + 65536, gA + 64, 0, wid, lane);
  stage_B8(ldsc + 98304, gB + 64, 0, wid, lane);
  asm volatile("s_waitcnt vmcnt(4)" ::: "memory");
  __builtin_amdgcn_s_barrier();

  const int NT = 32;
#pragma unroll 1
  for (int t = 0; t < NT; ++t) {
    const int bufOff = (t & 1) << 16;
    char* Ab = ldsc + bufOff;
    char* Bb = ldsc + 32768 + bufOff;
    char* An = ldsc + (bufOff ^ 65536);
    char* Bn = ldsc + 32768 + (bufOff ^ 65536);

    // ---- phase 0: (mh0, nh0) ----
    READ_AF(Ab, 0)
    READ_BF(Bb, 0, bf0)
    if (t + 1 < NT) stage_B8(Bn, gB + (t + 1) * 64, 1, wid, lane);
    __builtin_amdgcn_s_barrier();
    asm volatile("s_waitcnt lgkmcnt(0)" ::: "memory");
    __builtin_amdgcn_sched_barrier(0);
    __builtin_amdgcn_s_setprio(1);
    MFMA_Q(0, bf0, 0)
    __builtin_amdgcn_s_setprio(0);
    __builtin_amdgcn_s_barrier();

    // ---- phase 1: (mh0, nh1) ----
    READ_BF(Bb, 1, bf1)
    if (t + 1 < NT) stage_A8(An, gA + (t + 1) * 64, 1, wid, lane);
    __builtin_amdgcn_s_barrier();
    asm volatile("s_waitcnt lgkmcnt(0)" ::: "memory");
    __builtin_amdgcn_sched_barrier(0);
    __builtin_amdgcn_s_setprio(1);
    MFMA_Q(0, bf1, 1)
    __builtin_amdgcn_s_setprio(0);
    __builtin_amdgcn_s_barrier();

    // ---- phase 2: (mh1, nh0) ----
    READ_AF(Ab, 1)
    if (t + 2 < NT) stage_A8(Ab, gA + (t + 2) * 64, 0, wid, lane);
    __builtin_amdgcn_s_barrier();
    asm volatile("s_waitcnt lgkmcnt(0)" ::: "memory");
    __builtin_amdgcn_sched_barrier(0);
    __builtin_amdgcn_s_setprio(1);
    MFMA_Q(1, bf0, 0)
    __builtin_amdgcn_s_setprio(0);
    __builtin_amdgcn_s_barrier();

    // ---- phase 3: (mh1, nh1) ----
    if (t + 2 < NT) stage_B8(Bb, gB + (t + 2) * 64, 0, wid, lane);
    __builtin_amdgcn_s_barrier();
    __builtin_amdgcn_s_setprio(1);
    MFMA_Q(1, bf1, 1)
    __builtin_amdgcn_s_setprio(0);
    if (t + 2 < NT) {
      asm volatile("s_waitcnt vmcnt(4)" ::: "memory");
    } else if (t + 1 < NT) {
      asm volatile("s_waitcnt vmcnt(0)" ::: "memory");
    }
    __builtin_amdgcn_s_barrier();
  }

  // epilogue: C write (bf16), mfma32 C layout (validated by R9)
#pragma unroll
  for (int q = 0; q < 4; ++q) {
    int base_row = m0 + wm * 128 + (q >> 1) * 64 + (q & 1) * 32;
#pragma unroll
    for (int nh = 0; nh < 2; ++nh) {
      int col = n0 + wn * 64 + nh * 32 + l31;
#pragma unroll
      for (int reg = 0; reg < 16; ++reg) {
        int row = base_row + (reg & 3) + 8 * (reg >> 2) + 4 * hi;
        C[(size_t)row * 2048 + col] = f2bf(acc[q][nh][reg]);
      }
    }
  }
#undef READ_AF
#undef READ_BF
#undef MFMA_Q
}

// ---------------------------------------------------------------------------
// K6: final GEMM, fp32 out with c/x segment remap (m97 structure, unchanged)
// ---------------------------------------------------------------------------
__global__ __launch_bounds__(256) void gemm_out(
    const unsigned short* __restrict__ A,
    const unsigned short* __restrict__ B1t,
    const unsigned short* __restrict__ B2t,
    float* __restrict__ Co) {
  __shared__ __align__(16) unsigned short As[128 * 32];
  __shared__ __align__(16) unsigned short Bs[128 * 32];
  const int m0 = blockIdx.y * 128, n0 = blockIdx.x * 128;
  const unsigned short* Bt = ((m0 & 2047) < 256) ? B1t : B2t;
  const int tid = threadIdx.x, wid = tid >> 6, lane = tid & 63;
  const int g = lane >> 4, l15 = lane & 15;
  const int wm = wid >> 1, wn = wid & 1;
  const int srow = lane >> 2, skk = (lane & 3) * 8;
  f32x4 acc[4][4] = {};
  for (int k0 = 0; k0 < 2048; k0 += 32) {
#pragma unroll
    for (int rep = 0; rep < 2; ++rep) {
      int ia = wid * 2 + rep;
      gload_lds16(&A[(size_t)(m0 + ia * 16 + srow) * 2048 + k0 + skk], (char*)As + ia * 1024);
      gload_lds16(&Bt[(size_t)(n0 + ia * 16 + srow) * 2048 + k0 + skk], (char*)Bs + ia * 1024);
    }
    __syncthreads();
    short8 a[4], bb[4];
#pragma unroll
    for (int mf = 0; mf < 4; ++mf) a[mf] = *(const short8*)&As[(wm * 64 + mf * 16 + l15) * 32 + g * 8];
#pragma unroll
    for (int nf = 0; nf < 4; ++nf) bb[nf] = *(const short8*)&Bs[(wn * 64 + nf * 16 + l15) * 32 + g * 8];
#pragma unroll
    for (int mf = 0; mf < 4; ++mf)
#pragma unroll
      for (int nf = 0; nf < 4; ++nf)
        acc[mf][nf] = mfma16(a[mf], bb[nf], acc[mf][nf]);
    __syncthreads();
  }
#pragma unroll
  for (int mf = 0; mf < 4; ++mf)
#pragma unroll
    for (int r = 0; r < 4; ++r) {
      int row = m0 + wm * 64 + mf * 16 + 4 * g + r;
      int b = row >> 11, s = row & 2047;
      size_t dst = (s < 256) ? ((size_t)b * 256 + s) * 2048
                             : 1048576ull + ((size_t)b * 1792 + (s - 256)) * 2048;
#pragma unroll
      for (int nf = 0; nf < 4; ++nf)
        Co[dst + n0 + wn * 64 + nf * 16 + l15] = acc[mf][nf][r];
    }
}

// ---------------------------------------------------------------------------
// K4: fused LayerNorm+RoPE for BOTH q and k (R12 version, -10 us win).
// ---------------------------------------------------------------------------
__global__ __launch_bounds__(256) void ln_rope2(
    const unsigned short* __restrict__ P,
    const float* __restrict__ qw1, const float* __restrict__ qb1,
    const float* __restrict__ qw2, const float* __restrict__ qb2,
    const float* __restrict__ kw1, const float* __restrict__ kb1,
    const float* __restrict__ kw2, const float* __restrict__ kb2,
    const float* __restrict__ fre, const float* __restrict__ fim,
    unsigned short* __restrict__ Oa, float qscale) {
  int gid = blockIdx.x;
  int mat = gid >> 12;
  int row = gid & 4095;
  P += (size_t)mat * 8388608ull;
  Oa += (size_t)mat * 8388608ull;
  float oscale = mat ? 1.0f : qscale;
  int b = row >> 11, s = row & 2047;
  int pos = (s < 256) ? s : s - 256;
  const float* w = (s < 256) ? (mat ? kw1 : qw1) : (mat ? kw2 : qw2);
  const float* bb = (s < 256) ? (mat ? kb1 : qb1) : (mat ? kb2 : qb2);
  int t = threadIdx.x, lane = t & 63, wid = t >> 6;
  int col = t * 8;
  uint4 raw = *(const uint4*)&P[(size_t)row * 2048 + col];
  const unsigned short* rp = (const unsigned short*)&raw;
  float xv[8];
#pragma unroll
  for (int j = 0; j < 8; ++j) xv[j] = bf2f(rp[j]);
  float s1 = 0.f, s2 = 0.f;
#pragma unroll
  for (int j = 0; j < 8; ++j) { s1 += xv[j]; s2 += xv[j] * xv[j]; }
#pragma unroll
  for (int off = 32; off; off >>= 1) { s1 += __shfl_xor(s1, off); s2 += __shfl_xor(s2, off); }
  __shared__ float red1[4], red2[4];
  if (lane == 0) { red1[wid] = s1; red2[wid] = s2; }
  __syncthreads();
  s1 = red1[0] + red1[1] + red1[2] + red1[3];
  s2 = red2[0] + red2[1] + red2[2] + red2[3];
  float mean = s1 * (1.f / 2048.f);
  float var = s2 * (1.f / 2048.f) - mean * mean;
  float rs = rsqrtf(var + 1e-5f);
  float4 wv0 = *(const float4*)&w[col], wv1 = *(const float4*)&w[col + 4];
  float4 bv0 = *(const float4*)&bb[col], bv1 = *(const float4*)&bb[col + 4];
  float y[8];
  y[0] = (xv[0] - mean) * rs * wv0.x + bv0.x; y[1] = (xv[1] - mean) * rs * wv0.y + bv0.y;
  y[2] = (xv[2] - mean) * rs * wv0.z + bv0.z; y[3] = (xv[3] - mean) * rs * wv0.w + bv0.w;
  y[4] = (xv[4] - mean) * rs * wv1.x + bv1.x; y[5] = (xv[5] - mean) * rs * wv1.y + bv1.y;
  y[6] = (xv[6] - mean) * rs * wv1.z + bv1.z; y[7] = (xv[7] - mean) * rs * wv1.w + bv1.w;
#pragma unroll
  for (int j = 0; j < 8; ++j) y[j] *= oscale;
  int hd0 = col & 127;
  int i0 = hd0 >> 1;
  float4 fr = *(const float4*)&fre[(size_t)pos * 64 + i0];
  float4 fi = *(const float4*)&fim[(size_t)pos * 64 + i0];
  union { unsigned short us[8]; uint4 u; } pk;
  pk.us[0] = f2bf(y[0] * fr.x - y[1] * fi.x); pk.us[1] = f2bf(y[0] * fi.x + y[1] * fr.x);
  pk.us[2] = f2bf(y[2] * fr.y - y[3] * fi.y); pk.us[3] = f2bf(y[2] * fi.y + y[3] * fr.y);
  pk.us[4] = f2bf(y[4] * fr.z - y[5] * fi.z); pk.us[5] = f2bf(y[4] * fi.z + y[5] * fr.z);
  pk.us[6] = f2bf(y[6] * fr.w - y[7] * fi.w); pk.us[7] = f2bf(y[6] * fi.w + y[7] * fr.w);
  int h = col >> 7;
  *(uint4*)&Oa[((size_t)(b * 16 + h) * 2048 + s) * 128 + hd0] = pk.u;
}

// ---------------------------------------------------------------------------
// K4v: v transpose [4096][2048] -> [B][H][HD][S]
// ---------------------------------------------------------------------------
__global__ __launch_bounds__(256) void v_trans(const unsigned short* __restrict__ vp,
                                               unsigned short* __restrict__ va) {
  int bh = blockIdx.y;
  int b = bh >> 4, h = bh & 15;
  int s0 = blockIdx.x * 64;
  __shared__ unsigned short tile[64][128];
  int tid = threadIdx.x;
#pragma unroll
  for (int p = 0; p < 4; ++p) {
    int s = p * 16 + (tid >> 4);
    int d0 = (tid & 15) * 8;
    *(uint4*)&tile[s][d0] = *(const uint4*)&vp[((size_t)b * 2048 + s0 + s) * 2048 + h * 128 + d0];
  }
  __syncthreads();
#pragma unroll
  for (int p = 0; p < 4; ++p) {
    int d = p * 32 + (tid >> 3);
    int soff = (tid & 7) * 8;
    union { unsigned short us[8]; uint4 u; } pk;
#pragma unroll
    for (int u = 0; u < 8; ++u) pk.us[u] = tile[soff + u][d];
    *(uint4*)&va[((size_t)(b * 16 + h) * 128 + d) * 2048 + s0 + soff] = pk.u;
  }
}

// ---------------------------------------------------------------------------
// K5: flash attention, 8-warp 32x32 swapped-operand, 4-deep KV buffers
// (R11/R12 version, unchanged).
// ---------------------------------------------------------------------------
#define THR_LOG2 11.5f

__global__ __launch_bounds__(512) void attn_kernel(
    const unsigned short* __restrict__ Q,
    const unsigned short* __restrict__ Kb,
    const unsigned short* __restrict__ Vt,
    unsigned short* __restrict__ O) {
  extern __shared__ __align__(16) char asmem[];
  const int q0 = blockIdx.x * 256;
  const int h = blockIdx.y, b = blockIdx.z;
  const int tid = threadIdx.x, wid = tid >> 6, lane = tid & 63;
  const int l31 = lane & 31, hi = lane >> 5;
  const size_t base = (size_t)(b * 16 + h) * 2048 * 128;
  const unsigned short* kbase = Kb + base;
  const unsigned short* vbase = Vt + base;

  const int qrow = q0 + wid * 32 + l31;
  short8 qf[8];
#pragma unroll
  for (int ks = 0; ks < 8; ++ks)
    qf[ks] = *(const short8*)&Q[base + (size_t)qrow * 128 + ks * 16 + hi * 8];

  f32x16 o_acc[4] = {};
  float m_run = -1e30f, l_run = 0.f;

#define STAGE(bufi, kv0)                                                             \
  {                                                                                  \
_Pragma("unroll")                                                                    \
    for (int p = 0; p < 2; ++p) {                                                    \
      int slot = p * 512 + wid * 64 + lane;                                          \
      int row = slot >> 4;                                                           \
      int u = (slot & 15) ^ (row & 7);                                               \
      gload_lds16(&kbase[(size_t)((kv0) + row) * 128 + u * 8],                       \
                  asmem + (bufi) * 32768 + (p * 512 + wid * 64) * 16);               \
    }                                                                                \
_Pragma("unroll")                                                                    \
    for (int p = 0; p < 2; ++p) {                                                    \
      int slot = p * 512 + wid * 64 + lane;                                          \
      int d = slot >> 3;                                                             \
      int u = (slot & 7) ^ (d & 7);                                                  \
      gload_lds16(&vbase[(size_t)d * 2048 + (kv0) + u * 8],                          \
                  asmem + (bufi) * 32768 + 16384 + (p * 512 + wid * 64) * 16);       \
    }                                                                                \
  }

  STAGE(0, 0)
  STAGE(1, 64)

#pragma unroll 1
  for (int t = 0; t < 32; ++t) {
    if (t + 2 < 32) {
      STAGE((t + 2) & 3, (t + 2) * 64)
      asm volatile("s_waitcnt vmcnt(8)" ::: "memory");
    } else if (t + 1 < 32) {
      asm volatile("s_waitcnt vmcnt(4)" ::: "memory");
    } else {
      asm volatile("s_waitcnt vmcnt(0)" ::: "memory");
    }
    __builtin_amdgcn_s_barrier();

    const char* Ksb = asmem + (t & 3) * 32768;
    const char* Vsb = Ksb + 16384;

    f32x16 sT0 = {}, sT1 = {};
    __builtin_amdgcn_s_setprio(1);
#pragma unroll
    for (int ks = 0; ks < 8; ++ks) {
      int unit = ks * 2 + hi;
      int r0 = l31;
      short8 kf0 = *(const short8*)(Ksb + ((r0 * 16 + (unit ^ (r0 & 7))) << 4));
      sT0 = mfma32(kf0, qf[ks], sT0);
      int r1 = 32 + l31;
      short8 kf1 = *(const short8*)(Ksb + ((r1 * 16 + (unit ^ (r1 & 7))) << 4));
      sT1 = mfma32(kf1, qf[ks], sT1);
    }
    __builtin_amdgcn_s_setprio(0);

    float mx = sT0[0];
#pragma unroll
    for (int r = 1; r < 16; ++r) mx = fmaxf(mx, sT0[r]);
#pragma unroll
    for (int r = 0; r < 16; ++r) mx = fmaxf(mx, sT1[r]);
    mx = fmaxf(mx, __shfl_xor(mx, 32));
    if (!__all(mx <= m_run + THR_LOG2)) {
      float mn = fmaxf(m_run, mx);
      float corr = __builtin_exp2f(m_run - mn);
      m_run = mn;
      l_run *= corr;
#pragma unroll
      for (int di = 0; di < 4; ++di)
#pragma unroll
        for (int r = 0; r < 16; ++r) o_acc[di][r] *= corr;
    }
    float ts = 0.f;
#pragma unroll
    for (int r = 0; r < 16; ++r) { sT0[r] = __builtin_exp2f(sT0[r] - m_run); ts += sT0[r]; }
#pragma unroll
    for (int r = 0; r < 16; ++r) { sT1[r] = __builtin_exp2f(sT1[r] - m_run); ts += sT1[r]; }
    ts += __shfl_xor(ts, 32);
    l_run += ts;

    unsigned int w0[8], w1[8];
#pragma unroll
    for (int j = 0; j < 8; ++j) {
      w0[j] = cvtpk(sT0[2 * j], sT0[2 * j + 1]);
      w1[j] = cvtpk(sT1[2 * j], sT1[2 * j + 1]);
    }
    unsigned int y0[4], y1[4];
    y0[0] = __shfl_xor((int)(hi ? w0[0] : w0[2]), 32);
    y0[1] = __shfl_xor((int)(hi ? w0[1] : w0[3]), 32);
    y0[2] = __shfl_xor((int)(hi ? w0[4] : w0[6]), 32);
    y0[3] = __shfl_xor((int)(hi ? w0[5] : w0[7]), 32);
    y1[0] = __shfl_xor((int)(hi ? w1[0] : w1[2]), 32);
    y1[1] = __shfl_xor((int)(hi ? w1[1] : w1[3]), 32);
    y1[2] = __shfl_xor((int)(hi ? w1[4] : w1[6]), 32);
    y1[3] = __shfl_xor((int)(hi ? w1[5] : w1[7]), 32);
    union { unsigned int u[4]; short8 s8; } pf[2][2];
    pf[0][0].u[0] = hi ? y0[0] : w0[0]; pf[0][0].u[1] = hi ? y0[1] : w0[1];
    pf[0][0].u[2] = hi ? w0[2] : y0[0]; pf[0][0].u[3] = hi ? w0[3] : y0[1];
    pf[0][1].u[0] = hi ? y0[2] : w0[4]; pf[0][1].u[1] = hi ? y0[3] : w0[5];
    pf[0][1].u[2] = hi ? w0[6] : y0[2]; pf[0][1].u[3] = hi ? w0[7] : y0[3];
    pf[1][0].u[0] = hi ? y1[0] : w1[0]; pf[1][0].u[1] = hi ? y1[1] : w1[1];
    pf[1][0].u[2] = hi ? w1[2] : y1[0]; pf[1][0].u[3] = hi ? w1[3] : y1[1];
    pf[1][1].u[0] = hi ? y1[2] : w1[4]; pf[1][1].u[1] = hi ? y1[3] : w1[5];
    pf[1][1].u[2] = hi ? w1[6] : y1[2]; pf[1][1].u[3] = hi ? w1[7] : y1[3];

    __builtin_amdgcn_s_setprio(1);
#pragma unroll
    for (int di = 0; di < 4; ++di) {
      int row = di * 32 + l31;
      int sw = row & 7;
#pragma unroll
      for (int kb = 0; kb < 2; ++kb)
#pragma unroll
        for (int ks2 = 0; ks2 < 2; ++ks2) {
          int unit = kb * 4 + ks2 * 2 + hi;
          short8 vf = *(const short8*)(Vsb + ((row * 8 + (unit ^ sw)) << 4));
          o_acc[di] = mfma32(vf, pf[kb][ks2].s8, o_acc[di]);
        }
    }
    __builtin_amdgcn_s_setprio(0);
  }

  float inv = 1.0f / l_run;
  char* ow = asmem + wid * 8192;
#pragma unroll
  for (int di = 0; di < 4; ++di)
#pragma unroll
    for (int rg = 0; rg < 4; ++rg) {
      unsigned int lo = cvtpk(o_acc[di][rg * 4 + 0] * inv, o_acc[di][rg * 4 + 1] * inv);
      unsigned int hi_w = cvtpk(o_acc[di][rg * 4 + 2] * inv, o_acc[di][rg * 4 + 3] * inv);
      int byte = (l31 * 256 + di * 64 + rg * 16 + hi * 8) ^ ((l31 & 7) << 4);
      *(unsigned long long*)(ow + byte) =
          ((unsigned long long)hi_w << 32) | (unsigned long long)lo;
    }
  asm volatile("s_waitcnt lgkmcnt(0)" ::: "memory");
  size_t obase = ((size_t)b * 2048 + q0 + wid * 32) * 2048 + (size_t)h * 128;
#pragma unroll
  for (int it = 0; it < 8; ++it) {
    int q = it * 4 + (lane >> 4);
    int d0 = (lane & 15) * 8;
    int byte = (q * 256 + d0 * 2) ^ ((q & 7) << 4);
    uint4 val = *(const uint4*)(ow + byte);
    *(uint4*)&O[obase + (size_t)q * 2048 + d0] = val;
  }
}

// ---------------------------------------------------------------------------
extern "C" void kernel_launch(void* const* d_in, const int* in_sizes, int n_in,
                              void* d_out, int out_size, void* d_ws, size_t ws_size,
                              hipStream_t stream) {
  (void)in_sizes; (void)n_in; (void)out_size; (void)ws_size;
  const float* c = (const float*)d_in[0];
  const float* x = (const float*)d_in[1];
  const float* fre = (const float*)d_in[2];
  const float* fim = (const float*)d_in[3];

  char* ws = (char*)d_ws;
  const size_t M2 = 2048ull * 2048ull;
  unsigned short* tb = (unsigned short*)ws;                    // 16 MB
  unsigned short* Wt = (unsigned short*)(ws + 16777216ull);    // 64 MB (8 matrices)
  unsigned short* qkv = (unsigned short*)(ws + 83886080ull);   // qp,kp,vp contiguous 48 MB
  unsigned short* qp = qkv;
  unsigned short* vp = (unsigned short*)(ws + 117440512ull);
  unsigned short* qa = (unsigned short*)(ws + 134217728ull);
  unsigned short* ka = (unsigned short*)(ws + 150994944ull);
  unsigned short* va = (unsigned short*)(ws + 167772160ull);
  unsigned short* attn_out = qp;  // reuse (qp dead after ln_rope2 q)

  (void)hipFuncSetAttribute((const void*)gemm_qkv3_8ph,
                            hipFuncAttributeMaxDynamicSharedMemorySize, 131072);
  (void)hipFuncSetAttribute((const void*)attn_kernel,
                            hipFuncAttributeMaxDynamicSharedMemorySize, 131072);

  conv_tb<<<4096, 256, 0, stream>>>(c, x, tb);
  trans_w<<<dim3(32, 32, 8), 256, 0, stream>>>(
      (const float*)d_in[4], (const float*)d_in[5], (const float*)d_in[6], (const float*)d_in[7],
      (const float*)d_in[8], (const float*)d_in[9], (const float*)d_in[10], (const float*)d_in[11],
      Wt);
  gemm_qkv3_8ph<<<384, 512, 131072, stream>>>(tb, Wt, qkv);
  ln_rope2<<<8192, 256, 0, stream>>>(qp,
                                     (const float*)d_in[12], (const float*)d_in[16],
                                     (const float*)d_in[14], (const float*)d_in[18],
                                     (const float*)d_in[13], (const float*)d_in[17],
                                     (const float*)d_in[15], (const float*)d_in[19],
                                     fre, fim, qa,
                                     0.08838834764831845f * 1.4426950408889634f);
  v_trans<<<dim3(32, 32), 256, 0, stream>>>(vp, va);
  attn_kernel<<<dim3(8, 16, 2), 512, 131072, stream>>>(qa, ka, va, attn_out);
  gemm_out<<<dim3(16, 32), 256, 0, stream>>>(attn_out, Wt + 3 * M2, Wt + 7 * M2, (float*)d_out);
}

// Round 14
// 334.449 us; speedup vs baseline: 1.0869x; 1.0869x over previous
//
#include <hip/hip_runtime.h>

typedef __attribute__((ext_vector_type(8))) short short8;
typedef __attribute__((ext_vector_type(4))) float f32x4;
typedef __attribute__((ext_vector_type(16))) float f32x16;

#define DEV __device__ __forceinline__

DEV unsigned short f2bf(float f) {
  unsigned int u; __builtin_memcpy(&u, &f, 4);
  u = (u + 0x7FFFu + ((u >> 16) & 1u)) >> 16;
  return (unsigned short)u;
}
DEV float bf2f(unsigned short h) {
  unsigned int u = ((unsigned int)h) << 16;
  float f; __builtin_memcpy(&f, &u, 4);
  return f;
}
DEV unsigned int cvtpk(float lo, float hi_) {
  unsigned int r;
  asm("v_cvt_pk_bf16_f32 %0, %1, %2" : "=v"(r) : "v"(lo), "v"(hi_));
  return r;
}

DEV void gload_lds16(const void* g, void* l) {
  __builtin_amdgcn_global_load_lds(
      (const __attribute__((address_space(1))) void*)g,
      (__attribute__((address_space(3))) void*)l, 16, 0, 0);
}

DEV f32x16 mfma32(short8 a, short8 b, f32x16 c) {
  return __builtin_amdgcn_mfma_f32_32x32x16_bf16(a, b, c, 0, 0, 0);
}
DEV f32x4 mfma16(short8 a, short8 b, f32x4 c) {
  return __builtin_amdgcn_mfma_f32_16x16x32_bf16(a, b, c, 0, 0, 0);
}

// ---------------------------------------------------------------------------
// K1: fp32 c,x -> bf16 concat tb [4096][2048]
// ---------------------------------------------------------------------------
__global__ __launch_bounds__(256) void conv_tb(const float* __restrict__ c,
                                               const float* __restrict__ x,
                                               unsigned short* __restrict__ tb) {
  int row = blockIdx.x;
  int b = row >> 11, s = row & 2047;
  const float* src = (s < 256) ? (c + (size_t)(b * 256 + s) * 2048)
                               : (x + (size_t)(b * 1792 + (s - 256)) * 2048);
  int t = threadIdx.x;
  float4 v0 = *(const float4*)&src[t * 8];
  float4 v1 = *(const float4*)&src[t * 8 + 4];
  union { unsigned short us[8]; uint4 u; } pk;
  pk.us[0] = f2bf(v0.x); pk.us[1] = f2bf(v0.y); pk.us[2] = f2bf(v0.z); pk.us[3] = f2bf(v0.w);
  pk.us[4] = f2bf(v1.x); pk.us[5] = f2bf(v1.y); pk.us[6] = f2bf(v1.z); pk.us[7] = f2bf(v1.w);
  *(uint4*)&tb[(size_t)row * 2048 + t * 8] = pk.u;
}

// ---------------------------------------------------------------------------
// K2: transpose+convert 8 weights: W [K][N] f32 -> Wt [N][K] bf16
// ---------------------------------------------------------------------------
__global__ __launch_bounds__(256) void trans_w(
    const float* __restrict__ w0, const float* __restrict__ w1,
    const float* __restrict__ w2, const float* __restrict__ w3,
    const float* __restrict__ w4, const float* __restrict__ w5,
    const float* __restrict__ w6, const float* __restrict__ w7,
    unsigned short* __restrict__ dstbase) {
  const float* W;
  switch (blockIdx.z) {
    case 0: W = w0; break; case 1: W = w1; break; case 2: W = w2; break; case 3: W = w3; break;
    case 4: W = w4; break; case 5: W = w5; break; case 6: W = w6; break; default: W = w7; break;
  }
  unsigned short* Wt = dstbase + (size_t)blockIdx.z * 2048 * 2048;
  __shared__ float tile[64][65];
  int n0 = blockIdx.x * 64, k0 = blockIdx.y * 64;
  int j = threadIdx.x & 63, i0 = threadIdx.x >> 6;
#pragma unroll
  for (int p = 0; p < 16; ++p) {
    int i = i0 + p * 4;
    tile[i][j] = W[(size_t)(k0 + i) * 2048 + n0 + j];
  }
  __syncthreads();
#pragma unroll
  for (int p = 0; p < 16; ++p) {
    int i = i0 + p * 4;
    Wt[(size_t)(n0 + i) * 2048 + k0 + j] = f2bf(tile[j][i]);
  }
}

// ---------------------------------------------------------------------------
// K3: fused QKV GEMM, 256x256 tile, BK=64, 8 waves, 16x16x32 MFMA.
// EXACT R6 4-phase schedule — best measured (128.8-130.3 us, 0 bank
// conflicts). Both 32x32-MFMA attempts (R9, R13) reintroduced 9.4e6
// conflicts via 32-row-span column reads; closed at source level.
// ---------------------------------------------------------------------------
DEV void stage_A8(char* ldsAbase, const unsigned short* gtile, int mh, int wid, int lane) {
#pragma unroll
  for (int p = 0; p < 2; ++p) {
    int row0 = mh * 64 + p * 128 + wid * 8;  // wave-uniform
    int row = row0 + (lane >> 3);
    int u = (lane & 7) ^ (row & 7);
    gload_lds16(gtile + (size_t)row * 2048 + u * 8, ldsAbase + row0 * 128);
  }
}
DEV void stage_B8(char* ldsBbase, const unsigned short* gtile, int nh, int wid, int lane) {
#pragma unroll
  for (int p = 0; p < 2; ++p) {
    int idx = p * 8 + wid;
    int row0 = (idx >> 2) * 64 + nh * 32 + (idx & 3) * 8;  // wave-uniform
    int row = row0 + (lane >> 3);
    int u = (lane & 7) ^ (row & 7);
    gload_lds16(gtile + (size_t)row * 2048 + u * 8, ldsBbase + row0 * 128);
  }
}

__global__ __launch_bounds__(512, 2) void gemm_qkv3_8ph(
    const unsigned short* __restrict__ A,
    const unsigned short* __restrict__ Wt,
    unsigned short* __restrict__ out) {
  extern __shared__ __align__(16) char ldsc[];
  const size_t M2 = 2048ull * 2048ull;
  int bid = blockIdx.x;
  int sw = (bid & 7) * 48 + (bid >> 3);   // bijective XCD swizzle (384 % 8 == 0)
  const int which = sw >> 7;
  const int rem = sw & 127;
  const int m0 = (rem >> 3) * 256, n0 = (rem & 7) * 256;
  const unsigned short* Bt = Wt + (size_t)(((m0 & 2047) < 256) ? which : which + 4) * M2;
  unsigned short* C = out + (size_t)which * (4096ull * 2048ull);
  const int tid = threadIdx.x, wid = tid >> 6, lane = tid & 63;
  const int g = lane >> 4, l15 = lane & 15;
  const int wm = wid >> 2, wn = wid & 3;
  const unsigned short* gA = A + (size_t)m0 * 2048;
  const unsigned short* gB = Bt + (size_t)n0 * 2048;

  f32x4 acc[8][4] = {};

  stage_A8(ldsc, gA, 0, wid, lane);
  stage_A8(ldsc, gA, 1, wid, lane);
  stage_B8(ldsc + 32768, gB, 0, wid, lane);
  stage_B8(ldsc + 32768, gB, 1, wid, lane);
  stage_A8(ldsc + 65536, gA + 64, 0, wid, lane);
  stage_B8(ldsc + 98304, gB + 64, 0, wid, lane);
  asm volatile("s_waitcnt vmcnt(4)" ::: "memory");
  __builtin_amdgcn_s_barrier();

  const int NT = 32;
#pragma unroll 1
  for (int t = 0; t < NT; ++t) {
    const int bufOff = (t & 1) << 16;
    char* Ab = ldsc + bufOff;
    char* Bb = ldsc + 32768 + bufOff;
    char* An = ldsc + (bufOff ^ 65536);
    char* Bn = ldsc + 32768 + (bufOff ^ 65536);
    short8 af[4][2], bf0[2][2], bf1[2][2];

    // phase 0: (mh0, nh0)
#pragma unroll
    for (int m4 = 0; m4 < 4; ++m4)
#pragma unroll
      for (int k2 = 0; k2 < 2; ++k2) {
        int row = wm * 128 + m4 * 16 + l15;
        af[m4][k2] = *(const short8*)(Ab + row * 128 + (((k2 * 4 + g) ^ (row & 7)) << 4));
      }
#pragma unroll
    for (int n2 = 0; n2 < 2; ++n2)
#pragma unroll
      for (int k2 = 0; k2 < 2; ++k2) {
        int row = wn * 64 + n2 * 16 + l15;
        bf0[n2][k2] = *(const short8*)(Bb + row * 128 + (((k2 * 4 + g) ^ (row & 7)) << 4));
      }
    if (t + 1 < NT) stage_B8(Bn, gB + (t + 1) * 64, 1, wid, lane);
    __builtin_amdgcn_s_barrier();
    asm volatile("s_waitcnt lgkmcnt(0)" ::: "memory");
    __builtin_amdgcn_sched_barrier(0);
    __builtin_amdgcn_s_setprio(1);
#pragma unroll
    for (int m4 = 0; m4 < 4; ++m4)
#pragma unroll
      for (int n2 = 0; n2 < 2; ++n2)
#pragma unroll
        for (int k2 = 0; k2 < 2; ++k2)
          acc[m4][n2] = mfma16(af[m4][k2], bf0[n2][k2], acc[m4][n2]);
    __builtin_amdgcn_s_setprio(0);
    __builtin_amdgcn_s_barrier();

    // phase 1: (mh0, nh1)
#pragma unroll
    for (int n2 = 0; n2 < 2; ++n2)
#pragma unroll
      for (int k2 = 0; k2 < 2; ++k2) {
        int row = wn * 64 + 32 + n2 * 16 + l15;
        bf1[n2][k2] = *(const short8*)(Bb + row * 128 + (((k2 * 4 + g) ^ (row & 7)) << 4));
      }
    if (t + 1 < NT) stage_A8(An, gA + (t + 1) * 64, 1, wid, lane);
    __builtin_amdgcn_s_barrier();
    asm volatile("s_waitcnt lgkmcnt(0)" ::: "memory");
    __builtin_amdgcn_sched_barrier(0);
    __builtin_amdgcn_s_setprio(1);
#pragma unroll
    for (int m4 = 0; m4 < 4; ++m4)
#pragma unroll
      for (int n2 = 0; n2 < 2; ++n2)
#pragma unroll
        for (int k2 = 0; k2 < 2; ++k2)
          acc[m4][2 + n2] = mfma16(af[m4][k2], bf1[n2][k2], acc[m4][2 + n2]);
    __builtin_amdgcn_s_setprio(0);
    __builtin_amdgcn_s_barrier();

    // phase 2: (mh1, nh0)
#pragma unroll
    for (int m4 = 0; m4 < 4; ++m4)
#pragma unroll
      for (int k2 = 0; k2 < 2; ++k2) {
        int row = wm * 128 + 64 + m4 * 16 + l15;
        af[m4][k2] = *(const short8*)(Ab + row * 128 + (((k2 * 4 + g) ^ (row & 7)) << 4));
      }
    if (t + 2 < NT) stage_A8(Ab, gA + (t + 2) * 64, 0, wid, lane);
    __builtin_amdgcn_s_barrier();
    asm volatile("s_waitcnt lgkmcnt(0)" ::: "memory");
    __builtin_amdgcn_sched_barrier(0);
    __builtin_amdgcn_s_setprio(1);
#pragma unroll
    for (int m4 = 0; m4 < 4; ++m4)
#pragma unroll
      for (int n2 = 0; n2 < 2; ++n2)
#pragma unroll
        for (int k2 = 0; k2 < 2; ++k2)
          acc[4 + m4][n2] = mfma16(af[m4][k2], bf0[n2][k2], acc[4 + m4][n2]);
    __builtin_amdgcn_s_setprio(0);
    __builtin_amdgcn_s_barrier();

    // phase 3: (mh1, nh1)
    if (t + 2 < NT) stage_B8(Bb, gB + (t + 2) * 64, 0, wid, lane);
    __builtin_amdgcn_s_barrier();
    __builtin_amdgcn_s_setprio(1);
#pragma unroll
    for (int m4 = 0; m4 < 4; ++m4)
#pragma unroll
      for (int n2 = 0; n2 < 2; ++n2)
#pragma unroll
        for (int k2 = 0; k2 < 2; ++k2)
          acc[4 + m4][2 + n2] = mfma16(af[m4][k2], bf1[n2][k2], acc[4 + m4][2 + n2]);
    __builtin_amdgcn_s_setprio(0);
    if (t + 2 < NT) {
      asm volatile("s_waitcnt vmcnt(4)" ::: "memory");
    } else if (t + 1 < NT) {
      asm volatile("s_waitcnt vmcnt(0)" ::: "memory");
    }
    __builtin_amdgcn_s_barrier();
  }

#pragma unroll
  for (int mh = 0; mh < 2; ++mh)
#pragma unroll
    for (int m4 = 0; m4 < 4; ++m4)
#pragma unroll
      for (int r = 0; r < 4; ++r) {
        int row = m0 + wm * 128 + mh * 64 + m4 * 16 + 4 * g + r;
#pragma unroll
        for (int nh = 0; nh < 2; ++nh)
#pragma unroll
          for (int n2 = 0; n2 < 2; ++n2)
            C[(size_t)row * 2048 + n0 + wn * 64 + nh * 32 + n2 * 16 + l15] =
                f2bf(acc[mh * 4 + m4][nh * 2 + n2][r]);
      }
}

// ---------------------------------------------------------------------------
// K6: final GEMM, fp32 out with c/x segment remap (m97 structure, unchanged)
// ---------------------------------------------------------------------------
__global__ __launch_bounds__(256) void gemm_out(
    const unsigned short* __restrict__ A,
    const unsigned short* __restrict__ B1t,
    const unsigned short* __restrict__ B2t,
    float* __restrict__ Co) {
  __shared__ __align__(16) unsigned short As[128 * 32];
  __shared__ __align__(16) unsigned short Bs[128 * 32];
  const int m0 = blockIdx.y * 128, n0 = blockIdx.x * 128;
  const unsigned short* Bt = ((m0 & 2047) < 256) ? B1t : B2t;
  const int tid = threadIdx.x, wid = tid >> 6, lane = tid & 63;
  const int g = lane >> 4, l15 = lane & 15;
  const int wm = wid >> 1, wn = wid & 1;
  const int srow = lane >> 2, skk = (lane & 3) * 8;
  f32x4 acc[4][4] = {};
  for (int k0 = 0; k0 < 2048; k0 += 32) {
#pragma unroll
    for (int rep = 0; rep < 2; ++rep) {
      int ia = wid * 2 + rep;
      gload_lds16(&A[(size_t)(m0 + ia * 16 + srow) * 2048 + k0 + skk], (char*)As + ia * 1024);
      gload_lds16(&Bt[(size_t)(n0 + ia * 16 + srow) * 2048 + k0 + skk], (char*)Bs + ia * 1024);
    }
    __syncthreads();
    short8 a[4], bb[4];
#pragma unroll
    for (int mf = 0; mf < 4; ++mf) a[mf] = *(const short8*)&As[(wm * 64 + mf * 16 + l15) * 32 + g * 8];
#pragma unroll
    for (int nf = 0; nf < 4; ++nf) bb[nf] = *(const short8*)&Bs[(wn * 64 + nf * 16 + l15) * 32 + g * 8];
#pragma unroll
    for (int mf = 0; mf < 4; ++mf)
#pragma unroll
      for (int nf = 0; nf < 4; ++nf)
        acc[mf][nf] = mfma16(a[mf], bb[nf], acc[mf][nf]);
    __syncthreads();
  }
#pragma unroll
  for (int mf = 0; mf < 4; ++mf)
#pragma unroll
    for (int r = 0; r < 4; ++r) {
      int row = m0 + wm * 64 + mf * 16 + 4 * g + r;
      int b = row >> 11, s = row & 2047;
      size_t dst = (s < 256) ? ((size_t)b * 256 + s) * 2048
                             : 1048576ull + ((size_t)b * 1792 + (s - 256)) * 2048;
#pragma unroll
      for (int nf = 0; nf < 4; ++nf)
        Co[dst + n0 + wn * 64 + nf * 16 + l15] = acc[mf][nf][r];
    }
}

// ---------------------------------------------------------------------------
// K4: fused LayerNorm+RoPE for BOTH q and k (R12 version, -10 us win).
// ---------------------------------------------------------------------------
__global__ __launch_bounds__(256) void ln_rope2(
    const unsigned short* __restrict__ P,
    const float* __restrict__ qw1, const float* __restrict__ qb1,
    const float* __restrict__ qw2, const float* __restrict__ qb2,
    const float* __restrict__ kw1, const float* __restrict__ kb1,
    const float* __restrict__ kw2, const float* __restrict__ kb2,
    const float* __restrict__ fre, const float* __restrict__ fim,
    unsigned short* __restrict__ Oa, float qscale) {
  int gid = blockIdx.x;
  int mat = gid >> 12;
  int row = gid & 4095;
  P += (size_t)mat * 8388608ull;
  Oa += (size_t)mat * 8388608ull;
  float oscale = mat ? 1.0f : qscale;
  int b = row >> 11, s = row & 2047;
  int pos = (s < 256) ? s : s - 256;
  const float* w = (s < 256) ? (mat ? kw1 : qw1) : (mat ? kw2 : qw2);
  const float* bb = (s < 256) ? (mat ? kb1 : qb1) : (mat ? kb2 : qb2);
  int t = threadIdx.x, lane = t & 63, wid = t >> 6;
  int col = t * 8;
  uint4 raw = *(const uint4*)&P[(size_t)row * 2048 + col];
  const unsigned short* rp = (const unsigned short*)&raw;
  float xv[8];
#pragma unroll
  for (int j = 0; j < 8; ++j) xv[j] = bf2f(rp[j]);
  float s1 = 0.f, s2 = 0.f;
#pragma unroll
  for (int j = 0; j < 8; ++j) { s1 += xv[j]; s2 += xv[j] * xv[j]; }
#pragma unroll
  for (int off = 32; off; off >>= 1) { s1 += __shfl_xor(s1, off); s2 += __shfl_xor(s2, off); }
  __shared__ float red1[4], red2[4];
  if (lane == 0) { red1[wid] = s1; red2[wid] = s2; }
  __syncthreads();
  s1 = red1[0] + red1[1] + red1[2] + red1[3];
  s2 = red2[0] + red2[1] + red2[2] + red2[3];
  float mean = s1 * (1.f / 2048.f);
  float var = s2 * (1.f / 2048.f) - mean * mean;
  float rs = rsqrtf(var + 1e-5f);
  float4 wv0 = *(const float4*)&w[col], wv1 = *(const float4*)&w[col + 4];
  float4 bv0 = *(const float4*)&bb[col], bv1 = *(const float4*)&bb[col + 4];
  float y[8];
  y[0] = (xv[0] - mean) * rs * wv0.x + bv0.x; y[1] = (xv[1] - mean) * rs * wv0.y + bv0.y;
  y[2] = (xv[2] - mean) * rs * wv0.z + bv0.z; y[3] = (xv[3] - mean) * rs * wv0.w + bv0.w;
  y[4] = (xv[4] - mean) * rs * wv1.x + bv1.x; y[5] = (xv[5] - mean) * rs * wv1.y + bv1.y;
  y[6] = (xv[6] - mean) * rs * wv1.z + bv1.z; y[7] = (xv[7] - mean) * rs * wv1.w + bv1.w;
#pragma unroll
  for (int j = 0; j < 8; ++j) y[j] *= oscale;
  int hd0 = col & 127;
  int i0 = hd0 >> 1;
  float4 fr = *(const float4*)&fre[(size_t)pos * 64 + i0];
  float4 fi = *(const float4*)&fim[(size_t)pos * 64 + i0];
  union { unsigned short us[8]; uint4 u; } pk;
  pk.us[0] = f2bf(y[0] * fr.x - y[1] * fi.x); pk.us[1] = f2bf(y[0] * fi.x + y[1] * fr.x);
  pk.us[2] = f2bf(y[2] * fr.y - y[3] * fi.y); pk.us[3] = f2bf(y[2] * fi.y + y[3] * fr.y);
  pk.us[4] = f2bf(y[4] * fr.z - y[5] * fi.z); pk.us[5] = f2bf(y[4] * fi.z + y[5] * fr.z);
  pk.us[6] = f2bf(y[6] * fr.w - y[7] * fi.w); pk.us[7] = f2bf(y[6] * fi.w + y[7] * fr.w);
  int h = col >> 7;
  *(uint4*)&Oa[((size_t)(b * 16 + h) * 2048 + s) * 128 + hd0] = pk.u;
}

// ---------------------------------------------------------------------------
// K4v: v transpose [4096][2048] -> [B][H][HD][S]
// ---------------------------------------------------------------------------
__global__ __launch_bounds__(256) void v_trans(const unsigned short* __restrict__ vp,
                                               unsigned short* __restrict__ va) {
  int bh = blockIdx.y;
  int b = bh >> 4, h = bh & 15;
  int s0 = blockIdx.x * 64;
  __shared__ unsigned short tile[64][128];
  int tid = threadIdx.x;
#pragma unroll
  for (int p = 0; p < 4; ++p) {
    int s = p * 16 + (tid >> 4);
    int d0 = (tid & 15) * 8;
    *(uint4*)&tile[s][d0] = *(const uint4*)&vp[((size_t)b * 2048 + s0 + s) * 2048 + h * 128 + d0];
  }
  __syncthreads();
#pragma unroll
  for (int p = 0; p < 4; ++p) {
    int d = p * 32 + (tid >> 3);
    int soff = (tid & 7) * 8;
    union { unsigned short us[8]; uint4 u; } pk;
#pragma unroll
    for (int u = 0; u < 8; ++u) pk.us[u] = tile[soff + u][d];
    *(uint4*)&va[((size_t)(b * 16 + h) * 128 + d) * 2048 + s0 + soff] = pk.u;
  }
}

// ---------------------------------------------------------------------------
// K5: flash attention, 8-warp 32x32 swapped-operand, 4-deep KV buffers
// (R11 version, unchanged).
// ---------------------------------------------------------------------------
#define THR_LOG2 11.5f

__global__ __launch_bounds__(512) void attn_kernel(
    const unsigned short* __restrict__ Q,
    const unsigned short* __restrict__ Kb,
    const unsigned short* __restrict__ Vt,
    unsigned short* __restrict__ O) {
  extern __shared__ __align__(16) char asmem[];
  const int q0 = blockIdx.x * 256;
  const int h = blockIdx.y, b = blockIdx.z;
  const int tid = threadIdx.x, wid = tid >> 6, lane = tid & 63;
  const int l31 = lane & 31, hi = lane >> 5;
  const size_t base = (size_t)(b * 16 + h) * 2048 * 128;
  const unsigned short* kbase = Kb + base;
  const unsigned short* vbase = Vt + base;

  const int qrow = q0 + wid * 32 + l31;
  short8 qf[8];
#pragma unroll
  for (int ks = 0; ks < 8; ++ks)
    qf[ks] = *(const short8*)&Q[base + (size_t)qrow * 128 + ks * 16 + hi * 8];

  f32x16 o_acc[4] = {};
  float m_run = -1e30f, l_run = 0.f;

#define STAGE(bufi, kv0)                                                             \
  {                                                                                  \
_Pragma("unroll")                                                                    \
    for (int p = 0; p < 2; ++p) {                                                    \
      int slot = p * 512 + wid * 64 + lane;                                          \
      int row = slot >> 4;                                                           \
      int u = (slot & 15) ^ (row & 7);                                               \
      gload_lds16(&kbase[(size_t)((kv0) + row) * 128 + u * 8],                       \
                  asmem + (bufi) * 32768 + (p * 512 + wid * 64) * 16);               \
    }                                                                                \
_Pragma("unroll")                                                                    \
    for (int p = 0; p < 2; ++p) {                                                    \
      int slot = p * 512 + wid * 64 + lane;                                          \
      int d = slot >> 3;                                                             \
      int u = (slot & 7) ^ (d & 7);                                                  \
      gload_lds16(&vbase[(size_t)d * 2048 + (kv0) + u * 8],                          \
                  asmem + (bufi) * 32768 + 16384 + (p * 512 + wid * 64) * 16);       \
    }                                                                                \
  }

  STAGE(0, 0)
  STAGE(1, 64)

#pragma unroll 1
  for (int t = 0; t < 32; ++t) {
    if (t + 2 < 32) {
      STAGE((t + 2) & 3, (t + 2) * 64)
      asm volatile("s_waitcnt vmcnt(8)" ::: "memory");
    } else if (t + 1 < 32) {
      asm volatile("s_waitcnt vmcnt(4)" ::: "memory");
    } else {
      asm volatile("s_waitcnt vmcnt(0)" ::: "memory");
    }
    __builtin_amdgcn_s_barrier();

    const char* Ksb = asmem + (t & 3) * 32768;
    const char* Vsb = Ksb + 16384;

    f32x16 sT0 = {}, sT1 = {};
    __builtin_amdgcn_s_setprio(1);
#pragma unroll
    for (int ks = 0; ks < 8; ++ks) {
      int unit = ks * 2 + hi;
      int r0 = l31;
      short8 kf0 = *(const short8*)(Ksb + ((r0 * 16 + (unit ^ (r0 & 7))) << 4));
      sT0 = mfma32(kf0, qf[ks], sT0);
      int r1 = 32 + l31;
      short8 kf1 = *(const short8*)(Ksb + ((r1 * 16 + (unit ^ (r1 & 7))) << 4));
      sT1 = mfma32(kf1, qf[ks], sT1);
    }
    __builtin_amdgcn_s_setprio(0);

    float mx = sT0[0];
#pragma unroll
    for (int r = 1; r < 16; ++r) mx = fmaxf(mx, sT0[r]);
#pragma unroll
    for (int r = 0; r < 16; ++r) mx = fmaxf(mx, sT1[r]);
    mx = fmaxf(mx, __shfl_xor(mx, 32));
    if (!__all(mx <= m_run + THR_LOG2)) {
      float mn = fmaxf(m_run, mx);
      float corr = __builtin_exp2f(m_run - mn);
      m_run = mn;
      l_run *= corr;
#pragma unroll
      for (int di = 0; di < 4; ++di)
#pragma unroll
        for (int r = 0; r < 16; ++r) o_acc[di][r] *= corr;
    }
    float ts = 0.f;
#pragma unroll
    for (int r = 0; r < 16; ++r) { sT0[r] = __builtin_exp2f(sT0[r] - m_run); ts += sT0[r]; }
#pragma unroll
    for (int r = 0; r < 16; ++r) { sT1[r] = __builtin_exp2f(sT1[r] - m_run); ts += sT1[r]; }
    ts += __shfl_xor(ts, 32);
    l_run += ts;

    unsigned int w0[8], w1[8];
#pragma unroll
    for (int j = 0; j < 8; ++j) {
      w0[j] = cvtpk(sT0[2 * j], sT0[2 * j + 1]);
      w1[j] = cvtpk(sT1[2 * j], sT1[2 * j + 1]);
    }
    unsigned int y0[4], y1[4];
    y0[0] = __shfl_xor((int)(hi ? w0[0] : w0[2]), 32);
    y0[1] = __shfl_xor((int)(hi ? w0[1] : w0[3]), 32);
    y0[2] = __shfl_xor((int)(hi ? w0[4] : w0[6]), 32);
    y0[3] = __shfl_xor((int)(hi ? w0[5] : w0[7]), 32);
    y1[0] = __shfl_xor((int)(hi ? w1[0] : w1[2]), 32);
    y1[1] = __shfl_xor((int)(hi ? w1[1] : w1[3]), 32);
    y1[2] = __shfl_xor((int)(hi ? w1[4] : w1[6]), 32);
    y1[3] = __shfl_xor((int)(hi ? w1[5] : w1[7]), 32);
    union { unsigned int u[4]; short8 s8; } pf[2][2];
    pf[0][0].u[0] = hi ? y0[0] : w0[0]; pf[0][0].u[1] = hi ? y0[1] : w0[1];
    pf[0][0].u[2] = hi ? w0[2] : y0[0]; pf[0][0].u[3] = hi ? w0[3] : y0[1];
    pf[0][1].u[0] = hi ? y0[2] : w0[4]; pf[0][1].u[1] = hi ? y0[3] : w0[5];
    pf[0][1].u[2] = hi ? w0[6] : y0[2]; pf[0][1].u[3] = hi ? w0[7] : y0[3];
    pf[1][0].u[0] = hi ? y1[0] : w1[0]; pf[1][0].u[1] = hi ? y1[1] : w1[1];
    pf[1][0].u[2] = hi ? w1[2] : y1[0]; pf[1][0].u[3] = hi ? w1[3] : y1[1];
    pf[1][1].u[0] = hi ? y1[2] : w1[4]; pf[1][1].u[1] = hi ? y1[3] : w1[5];
    pf[1][1].u[2] = hi ? w1[6] : y1[2]; pf[1][1].u[3] = hi ? w1[7] : y1[3];

    __builtin_amdgcn_s_setprio(1);
#pragma unroll
    for (int di = 0; di < 4; ++di) {
      int row = di * 32 + l31;
      int sw = row & 7;
#pragma unroll
      for (int kb = 0; kb < 2; ++kb)
#pragma unroll
        for (int ks2 = 0; ks2 < 2; ++ks2) {
          int unit = kb * 4 + ks2 * 2 + hi;
          short8 vf = *(const short8*)(Vsb + ((row * 8 + (unit ^ sw)) << 4));
          o_acc[di] = mfma32(vf, pf[kb][ks2].s8, o_acc[di]);
        }
    }
    __builtin_amdgcn_s_setprio(0);
  }

  float inv = 1.0f / l_run;
  char* ow = asmem + wid * 8192;
#pragma unroll
  for (int di = 0; di < 4; ++di)
#pragma unroll
    for (int rg = 0; rg < 4; ++rg) {
      unsigned int lo = cvtpk(o_acc[di][rg * 4 + 0] * inv, o_acc[di][rg * 4 + 1] * inv);
      unsigned int hi_w = cvtpk(o_acc[di][rg * 4 + 2] * inv, o_acc[di][rg * 4 + 3] * inv);
      int byte = (l31 * 256 + di * 64 + rg * 16 + hi * 8) ^ ((l31 & 7) << 4);
      *(unsigned long long*)(ow + byte) =
          ((unsigned long long)hi_w << 32) | (unsigned long long)lo;
    }
  asm volatile("s_waitcnt lgkmcnt(0)" ::: "memory");
  size_t obase = ((size_t)b * 2048 + q0 + wid * 32) * 2048 + (size_t)h * 128;
#pragma unroll
  for (int it = 0; it < 8; ++it) {
    int q = it * 4 + (lane >> 4);
    int d0 = (lane & 15) * 8;
    int byte = (q * 256 + d0 * 2) ^ ((q & 7) << 4);
    uint4 val = *(const uint4*)(ow + byte);
    *(uint4*)&O[obase + (size_t)q * 2048 + d0] = val;
  }
}

// ---------------------------------------------------------------------------
extern "C" void kernel_launch(void* const* d_in, const int* in_sizes, int n_in,
                              void* d_out, int out_size, void* d_ws, size_t ws_size,
                              hipStream_t stream) {
  (void)in_sizes; (void)n_in; (void)out_size; (void)ws_size;
  const float* c = (const float*)d_in[0];
  const float* x = (const float*)d_in[1];
  const float* fre = (const float*)d_in[2];
  const float* fim = (const float*)d_in[3];

  char* ws = (char*)d_ws;
  const size_t M2 = 2048ull * 2048ull;
  unsigned short* tb = (unsigned short*)ws;                    // 16 MB
  unsigned short* Wt = (unsigned short*)(ws + 16777216ull);    // 64 MB (8 matrices)
  unsigned short* qkv = (unsigned short*)(ws + 83886080ull);   // qp,kp,vp contiguous 48 MB
  unsigned short* qp = qkv;
  unsigned short* vp = (unsigned short*)(ws + 117440512ull);
  unsigned short* qa = (unsigned short*)(ws + 134217728ull);
  unsigned short* ka = (unsigned short*)(ws + 150994944ull);
  unsigned short* va = (unsigned short*)(ws + 167772160ull);
  unsigned short* attn_out = qp;  // reuse (qp dead after ln_rope2 q)

  (void)hipFuncSetAttribute((const void*)gemm_qkv3_8ph,
                            hipFuncAttributeMaxDynamicSharedMemorySize, 131072);
  (void)hipFuncSetAttribute((const void*)attn_kernel,
                            hipFuncAttributeMaxDynamicSharedMemorySize, 131072);

  conv_tb<<<4096, 256, 0, stream>>>(c, x, tb);
  trans_w<<<dim3(32, 32, 8), 256, 0, stream>>>(
      (const float*)d_in[4], (const float*)d_in[5], (const float*)d_in[6], (const float*)d_in[7],
      (const float*)d_in[8], (const float*)d_in[9], (const float*)d_in[10], (const float*)d_in[11],
      Wt);
  gemm_qkv3_8ph<<<384, 512, 131072, stream>>>(tb, Wt, qkv);
  ln_rope2<<<8192, 256, 0, stream>>>(qp,
                                     (const float*)d_in[12], (const float*)d_in[16],
                                     (const float*)d_in[14], (const float*)d_in[18],
                                     (const float*)d_in[13], (const float*)d_in[17],
                                     (const float*)d_in[15], (const float*)d_in[19],
                                     fre, fim, qa,
                                     0.08838834764831845f * 1.4426950408889634f);
  v_trans<<<dim3(32, 32), 256, 0, stream>>>(vp, va);
  attn_kernel<<<dim3(8, 16, 2), 512, 131072, stream>>>(qa, ka, va, attn_out);
  gemm_out<<<dim3(16, 32), 256, 0, stream>>>(attn_out, Wt + 3 * M2, Wt + 7 * M2, (float*)d_out);
}